// Round 2
// baseline (384.855 us; speedup 1.0000x reference)
//
#include <hip/hip_runtime.h>
#include <cstdint>
#include <cstddef>

// EdgeMessagePassingLayer: out = W @ (L @ rowsum(E)) + b
//   where L[i,j] = 1 iff i!=j and exists k!=i,j with A[i,k]==A[j,k]==1.
// cnt[i,j] = popc(bits_i & bits_j) - d_i*M[j,i] - M[i,j]*d_j  (exact ints)
// agg[i]   = sum_j [cnt>0 && i!=j] * e[j]
// out      = W @ agg + b

#define NN    4096
#define W32C  128            // uint32 words per packed row
#define TI    64             // i-tile per block
#define TJ    32             // j-tile per LDS stage
#define NTHR  256
#define JSPLIT 8
#define JT_PER_STRIP (NN / TJ / JSPLIT)   // 16

typedef unsigned int uint32;

// ---------------- pack A -> bits (ballot), coalesced ----------------
__global__ __launch_bounds__(256) void pack_kernel(const float* __restrict__ A,
                                                   uint32* __restrict__ bits) {
  const int row  = blockIdx.x;
  const int lane = threadIdx.x & 63;
  const int wave = threadIdx.x >> 6;
  const float* arow = A + (size_t)row * NN;
  for (int c0 = wave * 64; c0 < NN; c0 += 256) {
    float a = arow[c0 + lane];
    unsigned long long m = __ballot(a == 1.0f);
    if (lane == 0) {
      *reinterpret_cast<unsigned long long*>(&bits[(size_t)row * W32C + (c0 >> 5)]) = m;
    }
  }
}

// ---------------- e[j] = rowsum(E) ----------------
__global__ __launch_bounds__(256) void rowsum_kernel(const float* __restrict__ E,
                                                     float* __restrict__ e) {
  const int row = blockIdx.x;
  const float4* p = reinterpret_cast<const float4*>(E + (size_t)row * NN);
  float s = 0.f;
  for (int k = threadIdx.x; k < NN / 4; k += NTHR) {
    float4 v = p[k];
    s += v.x + v.y + v.z + v.w;
  }
#pragma unroll
  for (int m = 1; m < 64; m <<= 1) s += __shfl_xor(s, m);
  __shared__ float red[4];
  if ((threadIdx.x & 63) == 0) red[threadIdx.x >> 6] = s;
  __syncthreads();
  if (threadIdx.x == 0) e[row] = red[0] + red[1] + red[2] + red[3];
}

// ---------------- main: agg[i] += sum_j L[i,j]*e[j] ----------------
__global__ __launch_bounds__(256) void cnt_agg_kernel(const uint32* __restrict__ bits,
                                                      const float* __restrict__ e,
                                                      float* __restrict__ agg) {
  __shared__ uint32 ib[TI][W32C + 4];   // +4 words pad: keeps b128 alignment, breaks bank hotspot
  __shared__ uint32 jb[TJ][W32C + 4];
  const int t  = threadIdx.x;
  const int i0 = blockIdx.y * TI;
  const int ty = t >> 4;      // 16 i-groups of 4 rows
  const int tx = t & 15;      // 16 j-groups of 2 rows

  // stage i-bits: 8192 words, 4 words/thread/iter, coalesced
#pragma unroll
  for (int k = 0; k < 8; ++k) {
    int linear = k * (NTHR * 4) + t * 4;
    int row = linear >> 7, col = linear & 127;
    uint4 v = *reinterpret_cast<const uint4*>(&bits[(size_t)(i0 + row) * W32C + col]);
    *reinterpret_cast<uint4*>(&ib[row][col]) = v;
  }

  float aggLoc[4] = {0.f, 0.f, 0.f, 0.f};

  for (int jt = 0; jt < JT_PER_STRIP; ++jt) {
    const int j0 = (blockIdx.x * JT_PER_STRIP + jt) * TJ;
    __syncthreads();   // previous tile's compute (and ib stage) done
#pragma unroll
    for (int k = 0; k < 4; ++k) {
      int linear = k * (NTHR * 4) + t * 4;
      int row = linear >> 7, col = linear & 127;
      uint4 v = *reinterpret_cast<const uint4*>(&bits[(size_t)(j0 + row) * W32C + col]);
      *reinterpret_cast<uint4*>(&jb[row][col]) = v;
    }
    __syncthreads();

    int cnt[4][2] = {};
#pragma unroll 8
    for (int w = 0; w < W32C; w += 4) {
      uint4 iw[4], jw[2];
#pragma unroll
      for (int r = 0; r < 4; ++r)
        iw[r] = *reinterpret_cast<const uint4*>(&ib[ty * 4 + r][w]);
#pragma unroll
      for (int s = 0; s < 2; ++s)
        jw[s] = *reinterpret_cast<const uint4*>(&jb[tx * 2 + s][w]);
#pragma unroll
      for (int r = 0; r < 4; ++r)
#pragma unroll
        for (int s = 0; s < 2; ++s) {
          cnt[r][s] += __popc(iw[r].x & jw[s].x) + __popc(iw[r].y & jw[s].y)
                     + __popc(iw[r].z & jw[s].z) + __popc(iw[r].w & jw[s].w);
        }
    }

    // corrections (diagonal terms are bits of the staged rows) + accumulate
#pragma unroll
    for (int r = 0; r < 4; ++r) {
      const int i = i0 + ty * 4 + r;
      const uint32 d_i = (ib[ty * 4 + r][i >> 5] >> (i & 31)) & 1u;
#pragma unroll
      for (int s = 0; s < 2; ++s) {
        const int jl = tx * 2 + s;
        const int j  = j0 + jl;
        const uint32 Mji = (jb[jl][i >> 5] >> (i & 31)) & 1u;
        const uint32 Mij = (ib[ty * 4 + r][j >> 5] >> (j & 31)) & 1u;
        const uint32 d_j = (jb[jl][j >> 5] >> (j & 31)) & 1u;
        const int c = cnt[r][s] - (int)(d_i * Mji) - (int)(Mij * d_j);
        if (c > 0 && i != j) aggLoc[r] += e[j];
      }
    }
  }

  // reduce over tx within the wave (lanes differing in low 4 bits share ty)
#pragma unroll
  for (int m = 1; m < 16; m <<= 1)
#pragma unroll
    for (int r = 0; r < 4; ++r) aggLoc[r] += __shfl_xor(aggLoc[r], m);
  if (tx == 0) {
#pragma unroll
    for (int r = 0; r < 4; ++r) atomicAdd(&agg[i0 + ty * 4 + r], aggLoc[r]);
  }
}

// ---------------- out[o] = dot(W[o,:], agg) + b[o] ----------------
__global__ __launch_bounds__(256) void matvec_kernel(const float* __restrict__ Wm,
                                                     const float* __restrict__ bvec,
                                                     const float* __restrict__ agg,
                                                     float* __restrict__ out) {
  const int o = blockIdx.x;
  const float4* wp = reinterpret_cast<const float4*>(Wm + (size_t)o * NN);
  const float4* ap = reinterpret_cast<const float4*>(agg);
  float s = 0.f;
  for (int k = threadIdx.x; k < NN / 4; k += NTHR) {
    float4 w4 = wp[k];
    float4 a4 = ap[k];
    s += w4.x * a4.x + w4.y * a4.y + w4.z * a4.z + w4.w * a4.w;
  }
#pragma unroll
  for (int m = 1; m < 64; m <<= 1) s += __shfl_xor(s, m);
  __shared__ float red[4];
  if ((threadIdx.x & 63) == 0) red[threadIdx.x >> 6] = s;
  __syncthreads();
  // BUG FIX (R1): previous version wrote `s + bvec[o]` — wave 0's partial only,
  // dropping red[1..3] (≈3/4 of the dot product; matched the 1396 absmax).
  if (threadIdx.x == 0) out[o] = red[0] + red[1] + red[2] + red[3] + bvec[o];
}

extern "C" void kernel_launch(void* const* d_in, const int* in_sizes, int n_in,
                              void* d_out, int out_size, void* d_ws, size_t ws_size,
                              hipStream_t stream) {
  const float* A  = (const float*)d_in[0];   // [4096,4096] 0/1
  const float* E  = (const float*)d_in[1];   // [4096,4096]
  const float* Wm = (const float*)d_in[2];   // [4096,4096]
  const float* bv = (const float*)d_in[3];   // [4096]
  float* out = (float*)d_out;

  uint32* bits = (uint32*)d_ws;                                    // 2 MB
  float*  e    = (float*)((char*)d_ws + (2u << 20));               // 16 KB
  float*  agg  = (float*)((char*)d_ws + (2u << 20) + 16384);       // 16 KB

  hipMemsetAsync(agg, 0, NN * sizeof(float), stream);

  pack_kernel<<<NN, NTHR, 0, stream>>>(A, bits);
  rowsum_kernel<<<NN, NTHR, 0, stream>>>(E, e);
  cnt_agg_kernel<<<dim3(JSPLIT, NN / TI), NTHR, 0, stream>>>(bits, e, agg);
  matvec_kernel<<<NN, NTHR, 0, stream>>>(Wm, bv, agg, out);
}

// Round 3
// 215.718 us; speedup vs baseline: 1.7841x; 1.7841x over previous
//
#include <hip/hip_runtime.h>
#include <cstdint>
#include <cstddef>

// EdgeMessagePassingLayer: out = W @ (L @ rowsum(E)) + b
//   L[i,j] = 1 iff i!=j and exists k!=i,j with A[i,k]==A[j,k]==1.
// cnt[i,j] = popc(bits_i & bits_j) - d_i*M[j,i] - M[i,j]*d_j  (exact ints)
// EARLY EXIT: corrections <= 2, so partial popc >= 3 over ANY subset of k
// already proves cnt_corrected >= 1 -> L=1 (if i!=j). Chunk 0 (128 bits,
// mean popc 32 at p=0.25) resolves ~all pairs; exact fallback for the rest.
//
// bits layout: chunk-major bitsT[32][4096] (uint4 = 128 bits per row-chunk).

#define NN    4096
#define NCHUNK 32            // 32 chunks of 128 bits = 4096 bits per row
#define TI    64             // i-rows per block
#define STRIPJ 512           // j-rows per block (strip)
#define NTHR  256

typedef unsigned int uint32;

// ---------------- pack A -> bitsT (chunk-major), float4 + ballot ----------------
__global__ __launch_bounds__(256) void pack_kernel(const float* __restrict__ A,
                                                   uint32* __restrict__ bitsT) {
  const int row  = blockIdx.x;
  const int lane = threadIdx.x & 63;
  const int wv   = threadIdx.x >> 6;
  const float* arow = A + (size_t)row * NN;
  // span = 256 columns; lane reads float4 at cols [256s+4l, 256s+4l+4)
  for (int s = wv; s < 16; s += 4) {
    float4 v = *reinterpret_cast<const float4*>(&arow[s * 256 + 4 * lane]);
    unsigned long long b0 = __ballot(v.x == 1.0f);  // bit l = col 256s+4l+0
    unsigned long long b1 = __ballot(v.y == 1.0f);
    unsigned long long b2 = __ballot(v.z == 1.0f);
    unsigned long long b3 = __ballot(v.w == 1.0f);
    if (lane < 8) {
      // word q=lane covers cols [256s+32q, +32): bit 4k+m = bit(8q+k) of b_m
      const int base = lane * 8;
      uint32 wrd = 0;
#pragma unroll
      for (int k = 0; k < 8; ++k) {
        wrd |= (uint32)((b0 >> (base + k)) & 1ull) << (4 * k + 0);
        wrd |= (uint32)((b1 >> (base + k)) & 1ull) << (4 * k + 1);
        wrd |= (uint32)((b2 >> (base + k)) & 1ull) << (4 * k + 2);
        wrd |= (uint32)((b3 >> (base + k)) & 1ull) << (4 * k + 3);
      }
      const int widx  = s * 8 + lane;       // global word index (col>>5)
      const int chunk = widx >> 2;          // 4 words per chunk
      bitsT[((size_t)chunk * NN + row) * 4 + (widx & 3)] = wrd;
    }
  }
}

// ---------------- e[j] = rowsum(E) ----------------
__global__ __launch_bounds__(256) void rowsum_kernel(const float* __restrict__ E,
                                                     float* __restrict__ e) {
  const int row = blockIdx.x;
  const float4* p = reinterpret_cast<const float4*>(E + (size_t)row * NN);
  float s = 0.f;
  for (int k = threadIdx.x; k < NN / 4; k += NTHR) {
    float4 v = p[k];
    s += v.x + v.y + v.z + v.w;
  }
#pragma unroll
  for (int m = 1; m < 64; m <<= 1) s += __shfl_xor(s, m);
  __shared__ float red[4];
  if ((threadIdx.x & 63) == 0) red[threadIdx.x >> 6] = s;
  __syncthreads();
  if (threadIdx.x == 0) e[row] = red[0] + red[1] + red[2] + red[3];
}

// ---------------- main: agg[i] += sum_j L[i,j]*e[j], early-exit on chunk0 ----------------
__global__ __launch_bounds__(256) void cnt_agg_kernel(const uint32* __restrict__ bitsT,
                                                      const float* __restrict__ e,
                                                      float* __restrict__ agg) {
  __shared__ uint4 ic0[TI];        // chunk0 of i-rows   (1 KB)
  __shared__ uint4 jc0[STRIPJ];    // chunk0 of j-strip  (8 KB)
  __shared__ float es[STRIPJ];     // e[j] strip         (2 KB)

  const int t     = threadIdx.x;
  const int jbase = blockIdx.x * STRIPJ;
  const int i0    = blockIdx.y * TI;
  const uint4* bT4 = reinterpret_cast<const uint4*>(bitsT);

  // stage (coalesced: consecutive threads -> consecutive uint4)
  if (t < TI) ic0[t] = bT4[i0 + t];
  jc0[t]        = bT4[jbase + t];
  jc0[256 + t]  = bT4[jbase + 256 + t];
  es[t]         = e[jbase + t];
  es[256 + t]   = e[jbase + 256 + t];
  __syncthreads();

  const int ty = t >> 4;   // 16 i-groups of 4 rows
  const int tx = t & 15;   // j interleave

  uint4 iw[4];
#pragma unroll
  for (int r = 0; r < 4; ++r) iw[r] = ic0[ty * 4 + r];   // broadcast/2-way reads

  float acc[4] = {0.f, 0.f, 0.f, 0.f};

  for (int jj = 0; jj < STRIPJ / 16; ++jj) {
    const int jl = jj * 16 + tx;
    const int j  = jbase + jl;
    const uint4 jw = jc0[jl];
    const float ej = es[jl];
#pragma unroll
    for (int r = 0; r < 4; ++r) {
      const int i = i0 + ty * 4 + r;
      const int p = __popc(iw[r].x & jw.x) + __popc(iw[r].y & jw.y)
                  + __popc(iw[r].z & jw.z) + __popc(iw[r].w & jw.w);
      if (__builtin_expect(p > 2, 1)) {
        // cnt_total >= p >= 3 > corrections(<=2)  =>  L=1 when i!=j
        if (i != j) acc[r] += ej;
      } else {
        // exact fallback: full popcount over remaining chunks (L2-resident)
        int cnt = p;
        for (int c = 1; c < NCHUNK; ++c) {
          const uint4 a = bT4[(size_t)c * NN + i];
          const uint4 b = bT4[(size_t)c * NN + j];
          cnt += __popc(a.x & b.x) + __popc(a.y & b.y)
               + __popc(a.z & b.z) + __popc(a.w & b.w);
        }
        const uint32 d_i = (bitsT[(((size_t)(i >> 7) * NN) + i) * 4 + ((i >> 5) & 3)] >> (i & 31)) & 1u;
        const uint32 Mji = (bitsT[(((size_t)(i >> 7) * NN) + j) * 4 + ((i >> 5) & 3)] >> (i & 31)) & 1u;
        const uint32 Mij = (bitsT[(((size_t)(j >> 7) * NN) + i) * 4 + ((j >> 5) & 3)] >> (j & 31)) & 1u;
        const uint32 d_j = (bitsT[(((size_t)(j >> 7) * NN) + j) * 4 + ((j >> 5) & 3)] >> (j & 31)) & 1u;
        const int cc = cnt - (int)(d_i * Mji) - (int)(Mij * d_j);
        if (cc > 0 && i != j) acc[r] += ej;
      }
    }
  }

  // reduce across tx (16-lane groups within the wave), then one atomic per i-row
#pragma unroll
  for (int m = 1; m < 16; m <<= 1)
#pragma unroll
    for (int r = 0; r < 4; ++r) acc[r] += __shfl_xor(acc[r], m);
  if (tx == 0) {
#pragma unroll
    for (int r = 0; r < 4; ++r) atomicAdd(&agg[i0 + ty * 4 + r], acc[r]);
  }
}

// ---------------- out[o] = dot(W[o,:], agg) + b[o] ----------------
__global__ __launch_bounds__(256) void matvec_kernel(const float* __restrict__ Wm,
                                                     const float* __restrict__ bvec,
                                                     const float* __restrict__ agg,
                                                     float* __restrict__ out) {
  const int o = blockIdx.x;
  const float4* wp = reinterpret_cast<const float4*>(Wm + (size_t)o * NN);
  const float4* ap = reinterpret_cast<const float4*>(agg);
  float s = 0.f;
  for (int k = threadIdx.x; k < NN / 4; k += NTHR) {
    float4 w4 = wp[k];
    float4 a4 = ap[k];
    s += w4.x * a4.x + w4.y * a4.y + w4.z * a4.z + w4.w * a4.w;
  }
#pragma unroll
  for (int m = 1; m < 64; m <<= 1) s += __shfl_xor(s, m);
  __shared__ float red[4];
  if ((threadIdx.x & 63) == 0) red[threadIdx.x >> 6] = s;
  __syncthreads();
  if (threadIdx.x == 0) out[o] = red[0] + red[1] + red[2] + red[3] + bvec[o];
}

extern "C" void kernel_launch(void* const* d_in, const int* in_sizes, int n_in,
                              void* d_out, int out_size, void* d_ws, size_t ws_size,
                              hipStream_t stream) {
  const float* A  = (const float*)d_in[0];   // [4096,4096] 0/1
  const float* E  = (const float*)d_in[1];   // [4096,4096]
  const float* Wm = (const float*)d_in[2];   // [4096,4096]
  const float* bv = (const float*)d_in[3];   // [4096]
  float* out = (float*)d_out;

  uint32* bitsT = (uint32*)d_ws;                                   // 2 MB (chunk-major)
  float*  e     = (float*)((char*)d_ws + (2u << 20));              // 16 KB
  float*  agg   = (float*)((char*)d_ws + (2u << 20) + 16384);      // 16 KB

  hipMemsetAsync(agg, 0, NN * sizeof(float), stream);

  pack_kernel<<<NN, NTHR, 0, stream>>>(A, bitsT);
  rowsum_kernel<<<NN, NTHR, 0, stream>>>(E, e);
  cnt_agg_kernel<<<dim3(NN / STRIPJ, NN / TI), NTHR, 0, stream>>>(bitsT, e, agg);
  matvec_kernel<<<NN, NTHR, 0, stream>>>(Wm, bv, agg, out);
}

// Round 4
// 208.180 us; speedup vs baseline: 1.8487x; 1.0362x over previous
//
#include <hip/hip_runtime.h>
#include <cstdint>
#include <cstddef>

// EdgeMessagePassingLayer: out = W @ (L @ rowsum(E)) + b
//   L[i,j] = 1 iff i!=j and exists k!=i,j with A[i,k]==A[j,k]==1.
// cnt[i,j] = popc(bits_i & bits_j) - d_i*M[j,i] - M[i,j]*d_j  (exact ints)
// EARLY EXIT: corrections <= 2, so partial popc >= 3 over ANY subset of k
// already proves cnt_corrected >= 1 -> L=1 (if i!=j). Chunk 0 (128 bits,
// mean popc 32 at p=0.25) resolves ~all pairs; exact fallback otherwise.
// bits layout: chunk-major bitsT[32][4096] (uint4 = 128 bits per row-chunk).

#define NN     4096
#define NCHUNK 32
#define TI     64            // i-rows per cnt block
#define STRIPJ 256           // j-rows per cnt block
#define NTHR   256

typedef unsigned int uint32;

// ---------------- fused prep: pack A (blocks 0..4095), rowsum E (4096..8191),
// ---------------- block 0 also zeroes agg ----------------
__global__ __launch_bounds__(256) void prep_kernel(const float* __restrict__ A,
                                                   const float* __restrict__ E,
                                                   uint32* __restrict__ bitsT,
                                                   float* __restrict__ e,
                                                   float* __restrict__ agg) {
  const int b = blockIdx.x;
  const int t = threadIdx.x;
  if (b < NN) {
    // ---- pack row b of A into chunk-major bitsT ----
    const int lane = t & 63;
    const int wv   = t >> 6;
    const float* arow = A + (size_t)b * NN;
    for (int s = wv; s < 16; s += 4) {
      float4 v = *reinterpret_cast<const float4*>(&arow[s * 256 + 4 * lane]);
      unsigned long long b0 = __ballot(v.x == 1.0f);  // bit l = col 256s+4l+0
      unsigned long long b1 = __ballot(v.y == 1.0f);
      unsigned long long b2 = __ballot(v.z == 1.0f);
      unsigned long long b3 = __ballot(v.w == 1.0f);
      if (lane < 8) {
        // word q=lane covers cols [256s+32q, +32): bit 4k+m = bit(8q+k) of b_m
        const int base = lane * 8;
        uint32 wrd = 0;
#pragma unroll
        for (int k = 0; k < 8; ++k) {
          wrd |= (uint32)((b0 >> (base + k)) & 1ull) << (4 * k + 0);
          wrd |= (uint32)((b1 >> (base + k)) & 1ull) << (4 * k + 1);
          wrd |= (uint32)((b2 >> (base + k)) & 1ull) << (4 * k + 2);
          wrd |= (uint32)((b3 >> (base + k)) & 1ull) << (4 * k + 3);
        }
        const int widx  = s * 8 + lane;       // global word index (col>>5)
        const int chunk = widx >> 2;          // 4 words per 128-bit chunk
        bitsT[((size_t)chunk * NN + b) * 4 + (widx & 3)] = wrd;
      }
    }
    if (b == 0) {
      float4 z = make_float4(0.f, 0.f, 0.f, 0.f);
      float4* a4 = reinterpret_cast<float4*>(agg);
#pragma unroll
      for (int k = t; k < NN / 4; k += NTHR) a4[k] = z;
    }
  } else {
    // ---- rowsum of E row (b - NN) ----
    const int row = b - NN;
    const float4* p = reinterpret_cast<const float4*>(E + (size_t)row * NN);
    float s = 0.f;
    for (int k = t; k < NN / 4; k += NTHR) {
      float4 v = p[k];
      s += v.x + v.y + v.z + v.w;
    }
#pragma unroll
    for (int m = 1; m < 64; m <<= 1) s += __shfl_xor(s, m);
    __shared__ float red[4];
    if ((t & 63) == 0) red[t >> 6] = s;
    __syncthreads();
    if (t == 0) e[row] = red[0] + red[1] + red[2] + red[3];
  }
}

// ---------------- main: agg[i] += sum_j L[i,j]*e[j], early-exit on chunk0 ----------------
__global__ __launch_bounds__(256) void cnt_agg_kernel(const uint32* __restrict__ bitsT,
                                                      const float* __restrict__ e,
                                                      float* __restrict__ agg) {
  __shared__ uint4 ic0[TI];        // chunk0 of i-rows   (1 KB)
  __shared__ uint4 jc0[STRIPJ];    // chunk0 of j-strip  (4 KB)
  __shared__ float es[STRIPJ];     // e[j] strip         (1 KB)

  const int t     = threadIdx.x;
  const int jbase = blockIdx.x * STRIPJ;
  const int i0    = blockIdx.y * TI;
  const uint4* bT4 = reinterpret_cast<const uint4*>(bitsT);

  // stage (coalesced: consecutive threads -> consecutive uint4)
  if (t < TI) ic0[t] = bT4[i0 + t];
  jc0[t] = bT4[jbase + t];
  es[t]  = e[jbase + t];
  __syncthreads();

  const int ty = t >> 4;   // 16 i-groups of 4 rows
  const int tx = t & 15;   // j interleave

  uint4 iw[4];
#pragma unroll
  for (int r = 0; r < 4; ++r) iw[r] = ic0[ty * 4 + r];   // broadcast reads

  float acc[4] = {0.f, 0.f, 0.f, 0.f};

  for (int jj = 0; jj < STRIPJ / 16; ++jj) {
    const int jl = jj * 16 + tx;
    const int j  = jbase + jl;
    const uint4 jw = jc0[jl];
    const float ej = es[jl];
#pragma unroll
    for (int r = 0; r < 4; ++r) {
      const int i = i0 + ty * 4 + r;
      const int p = __popc(iw[r].x & jw.x) + __popc(iw[r].y & jw.y)
                  + __popc(iw[r].z & jw.z) + __popc(iw[r].w & jw.w);
      if (__builtin_expect(p > 2, 1)) {
        // cnt_total >= p >= 3 > corrections(<=2)  =>  L=1 when i!=j
        if (i != j) acc[r] += ej;
      } else {
        // exact fallback: full popcount over remaining chunks (L2-resident)
        int cnt = p;
        for (int c = 1; c < NCHUNK; ++c) {
          const uint4 a = bT4[(size_t)c * NN + i];
          const uint4 b = bT4[(size_t)c * NN + j];
          cnt += __popc(a.x & b.x) + __popc(a.y & b.y)
               + __popc(a.z & b.z) + __popc(a.w & b.w);
        }
        const uint32 d_i = (bitsT[(((size_t)(i >> 7) * NN) + i) * 4 + ((i >> 5) & 3)] >> (i & 31)) & 1u;
        const uint32 Mji = (bitsT[(((size_t)(i >> 7) * NN) + j) * 4 + ((i >> 5) & 3)] >> (i & 31)) & 1u;
        const uint32 Mij = (bitsT[(((size_t)(j >> 7) * NN) + i) * 4 + ((j >> 5) & 3)] >> (j & 31)) & 1u;
        const uint32 d_j = (bitsT[(((size_t)(j >> 7) * NN) + j) * 4 + ((j >> 5) & 3)] >> (j & 31)) & 1u;
        const int cc = cnt - (int)(d_i * Mji) - (int)(Mij * d_j);
        if (cc > 0 && i != j) acc[r] += ej;
      }
    }
  }

  // reduce across tx (16-lane groups within the wave), then one atomic per i-row
#pragma unroll
  for (int m = 1; m < 16; m <<= 1)
#pragma unroll
    for (int r = 0; r < 4; ++r) acc[r] += __shfl_xor(acc[r], m);
  if (tx == 0) {
#pragma unroll
    for (int r = 0; r < 4; ++r) atomicAdd(&agg[i0 + ty * 4 + r], acc[r]);
  }
}

// ---------------- out[o] = dot(W[o,:], agg) + b[o] ----------------
__global__ __launch_bounds__(256) void matvec_kernel(const float* __restrict__ Wm,
                                                     const float* __restrict__ bvec,
                                                     const float* __restrict__ agg,
                                                     float* __restrict__ out) {
  const int o = blockIdx.x;
  const float4* wp = reinterpret_cast<const float4*>(Wm + (size_t)o * NN);
  const float4* ap = reinterpret_cast<const float4*>(agg);
  float s = 0.f;
  for (int k = threadIdx.x; k < NN / 4; k += NTHR) {
    float4 w4 = wp[k];
    float4 a4 = ap[k];
    s += w4.x * a4.x + w4.y * a4.y + w4.z * a4.z + w4.w * a4.w;
  }
#pragma unroll
  for (int m = 1; m < 64; m <<= 1) s += __shfl_xor(s, m);
  __shared__ float red[4];
  if ((threadIdx.x & 63) == 0) red[threadIdx.x >> 6] = s;
  __syncthreads();
  // all four wave partials (R1 bug: only wave 0's was added)
  if (threadIdx.x == 0) out[o] = red[0] + red[1] + red[2] + red[3] + bvec[o];
}

extern "C" void kernel_launch(void* const* d_in, const int* in_sizes, int n_in,
                              void* d_out, int out_size, void* d_ws, size_t ws_size,
                              hipStream_t stream) {
  const float* A  = (const float*)d_in[0];   // [4096,4096] 0/1
  const float* E  = (const float*)d_in[1];   // [4096,4096]
  const float* Wm = (const float*)d_in[2];   // [4096,4096]
  const float* bv = (const float*)d_in[3];   // [4096]
  float* out = (float*)d_out;

  uint32* bitsT = (uint32*)d_ws;                                   // 2 MB (chunk-major)
  float*  e     = (float*)((char*)d_ws + (2u << 20));              // 16 KB
  float*  agg   = (float*)((char*)d_ws + (2u << 20) + 16384);      // 16 KB

  prep_kernel<<<2 * NN, NTHR, 0, stream>>>(A, E, bitsT, e, agg);
  cnt_agg_kernel<<<dim3(NN / STRIPJ, NN / TI), NTHR, 0, stream>>>(bitsT, e, agg);
  matvec_kernel<<<NN, NTHR, 0, stream>>>(Wm, bv, agg, out);
}

// Round 6
// 192.668 us; speedup vs baseline: 1.9975x; 1.0805x over previous
//
#include <hip/hip_runtime.h>
#include <cstdint>
#include <cstddef>

// EdgeMessagePassingLayer: out = W @ (L @ rowsum(E)) + b
//   L[i,j] = 1 iff i!=j and exists k!=i,j with A[i,k]==A[j,k]==1.
// cnt[i,j] = popc(bits_i & bits_j) - d_i*M[j,i] - M[i,j]*d_j  (exact ints)
// EARLY EXIT: corrections <= 2, so partial popc >= 3 over ANY subset of k
// proves L=1 (if i!=j). Chunk 0 (128 bits, mean popc 32 at p=0.25) resolves
// ~all pairs; exact full-popcount fallback otherwise.
// bits layout: chunk-major bitsT[32][4096] (uint4 = 128 bits per row-chunk).

#define NN     4096
#define NCHUNK 32
#define TI     64            // i-rows per cnt block
#define STRIPJ 256           // j-rows per cnt block
#define NTHR   256

typedef unsigned int uint32;
typedef float f32x4 __attribute__((ext_vector_type(4)));   // clang vector: ok for nontemporal builtin

// nontemporal float4 load via ext_vector_type (float4 itself is a struct -> rejected by builtin)
__device__ __forceinline__ float4 ntload4(const float* p) {
  f32x4 v = __builtin_nontemporal_load(reinterpret_cast<const f32x4*>(p));
  return make_float4(v.x, v.y, v.z, v.w);
}

// ---------------- fused prep ----------------
// blocks 0..4095          : pack row b of A (ballot-free nibble+shfl path)
// blocks 4096..6143       : rowsum of E rows 2q, 2q+1  (8 indep loads/thread)
// block 0 additionally    : zero agg
__global__ __launch_bounds__(256) void prep_kernel(const float* __restrict__ A,
                                                   const float* __restrict__ E,
                                                   uint32* __restrict__ bitsT,
                                                   float* __restrict__ e,
                                                   float* __restrict__ agg) {
  const int b = blockIdx.x;
  const int t = threadIdx.x;
  if (b < NN) {
    // ---- pack: col c = 256s + 4*lane + m; word q covers cols [32q,32q+32) ----
    const int lane = t & 63;
    const int wv   = t >> 6;
    const float* arow = A + (size_t)b * NN;
#pragma unroll
    for (int s0 = 0; s0 < 4; ++s0) {
      const int s = wv + 4 * s0;          // 4 independent iterations per wave
      float4 v = ntload4(&arow[s * 256 + 4 * lane]);
      uint32 nib = (v.x == 1.0f ? 1u : 0u) | (v.y == 1.0f ? 2u : 0u)
                 | (v.z == 1.0f ? 4u : 0u) | (v.w == 1.0f ? 8u : 0u);
      uint32 w = nib << (4 * (lane & 7));
      w |= __shfl_xor(w, 1);
      w |= __shfl_xor(w, 2);
      w |= __shfl_xor(w, 4);              // every lane: full word of its 8-lane group
      if ((lane & 7) == 0) {
        const int widx = s * 8 + (lane >> 3);       // global word index (col>>5)
        bitsT[((size_t)(widx >> 2) * NN + b) * 4 + (widx & 3)] = w;
      }
    }
    if (b == 0) {
      float4 z = make_float4(0.f, 0.f, 0.f, 0.f);
      float4* a4 = reinterpret_cast<float4*>(agg);
      for (int k = t; k < NN / 4; k += NTHR) a4[k] = z;
    }
  } else {
    // ---- rowsum of E rows r0, r0+1 ----
    const int r0 = (b - NN) * 2;
    const float* p0 = E + (size_t)r0 * NN;
    const float* p1 = E + (size_t)(r0 + 1) * NN;
    float s0 = 0.f, s1 = 0.f;
#pragma unroll
    for (int it = 0; it < 4; ++it) {
      const int k = (t + it * NTHR) * 4;
      float4 v0 = ntload4(&p0[k]);
      float4 v1 = ntload4(&p1[k]);
      s0 += v0.x + v0.y + v0.z + v0.w;
      s1 += v1.x + v1.y + v1.z + v1.w;
    }
#pragma unroll
    for (int m = 1; m < 64; m <<= 1) { s0 += __shfl_xor(s0, m); s1 += __shfl_xor(s1, m); }
    __shared__ float red0[4], red1[4];
    if ((t & 63) == 0) { red0[t >> 6] = s0; red1[t >> 6] = s1; }
    __syncthreads();
    if (t == 0) {
      e[r0]     = red0[0] + red0[1] + red0[2] + red0[3];
      e[r0 + 1] = red1[0] + red1[1] + red1[2] + red1[3];
    }
  }
}

// ---------------- main: agg[i] += sum_j L[i,j]*e[j], early-exit on chunk0 ----------------
__global__ __launch_bounds__(256) void cnt_agg_kernel(const uint32* __restrict__ bitsT,
                                                      const float* __restrict__ e,
                                                      float* __restrict__ agg) {
  __shared__ uint4 ic0[TI];        // chunk0 of i-rows   (1 KB)
  __shared__ uint4 jc0[STRIPJ];    // chunk0 of j-strip  (4 KB)
  __shared__ float es[STRIPJ];     // e[j] strip         (1 KB)

  const int t     = threadIdx.x;
  const int jbase = blockIdx.x * STRIPJ;
  const int i0    = blockIdx.y * TI;
  const uint4* bT4 = reinterpret_cast<const uint4*>(bitsT);

  if (t < TI) ic0[t] = bT4[i0 + t];
  jc0[t] = bT4[jbase + t];
  es[t]  = e[jbase + t];
  __syncthreads();

  const int ty = t >> 4;   // 16 i-groups of 4 rows
  const int tx = t & 15;   // j interleave

  uint4 iw[4];
#pragma unroll
  for (int r = 0; r < 4; ++r) iw[r] = ic0[ty * 4 + r];   // broadcast reads

  float acc[4] = {0.f, 0.f, 0.f, 0.f};

  for (int jj = 0; jj < STRIPJ / 16; ++jj) {
    const int jl = jj * 16 + tx;
    const int j  = jbase + jl;
    const uint4 jw = jc0[jl];
    const float ej = es[jl];
#pragma unroll
    for (int r = 0; r < 4; ++r) {
      const int i = i0 + ty * 4 + r;
      const int p = __popc(iw[r].x & jw.x) + __popc(iw[r].y & jw.y)
                  + __popc(iw[r].z & jw.z) + __popc(iw[r].w & jw.w);
      if (__builtin_expect(p > 2, 1)) {
        if (i != j) acc[r] += ej;          // cnt >= 3 > corrections(<=2)
      } else {
        int cnt = p;                        // exact fallback (L2-resident bits)
        for (int c = 1; c < NCHUNK; ++c) {
          const uint4 a = bT4[(size_t)c * NN + i];
          const uint4 bb = bT4[(size_t)c * NN + j];
          cnt += __popc(a.x & bb.x) + __popc(a.y & bb.y)
               + __popc(a.z & bb.z) + __popc(a.w & bb.w);
        }
        const uint32 d_i = (bitsT[(((size_t)(i >> 7) * NN) + i) * 4 + ((i >> 5) & 3)] >> (i & 31)) & 1u;
        const uint32 Mji = (bitsT[(((size_t)(i >> 7) * NN) + j) * 4 + ((i >> 5) & 3)] >> (i & 31)) & 1u;
        const uint32 Mij = (bitsT[(((size_t)(j >> 7) * NN) + i) * 4 + ((j >> 5) & 3)] >> (j & 31)) & 1u;
        const uint32 d_j = (bitsT[(((size_t)(j >> 7) * NN) + j) * 4 + ((j >> 5) & 3)] >> (j & 31)) & 1u;
        const int cc = cnt - (int)(d_i * Mji) - (int)(Mij * d_j);
        if (cc > 0 && i != j) acc[r] += ej;
      }
    }
  }

#pragma unroll
  for (int m = 1; m < 16; m <<= 1)
#pragma unroll
    for (int r = 0; r < 4; ++r) acc[r] += __shfl_xor(acc[r], m);
  if (tx == 0) {
#pragma unroll
    for (int r = 0; r < 4; ++r) atomicAdd(&agg[i0 + ty * 4 + r], acc[r]);
  }
}

// ---------------- out[o] = dot(W[o,:], agg) + b[o], 2 outputs per block ----------------
__global__ __launch_bounds__(256) void matvec_kernel(const float* __restrict__ Wm,
                                                     const float* __restrict__ bvec,
                                                     const float* __restrict__ agg,
                                                     float* __restrict__ out) {
  const int o0 = blockIdx.x * 2;
  const float* w0 = Wm + (size_t)o0 * NN;
  const float* w1 = Wm + (size_t)(o0 + 1) * NN;
  const float4* ap = reinterpret_cast<const float4*>(agg);
  const int t = threadIdx.x;
  float s0 = 0.f, s1 = 0.f;
#pragma unroll
  for (int it = 0; it < 4; ++it) {
    const int k = t + it * NTHR;
    float4 a4 = ap[k];                 // L2/L3-resident, not nt
    float4 x0 = ntload4(&w0[k * 4]);
    float4 x1 = ntload4(&w1[k * 4]);
    s0 += x0.x * a4.x + x0.y * a4.y + x0.z * a4.z + x0.w * a4.w;
    s1 += x1.x * a4.x + x1.y * a4.y + x1.z * a4.z + x1.w * a4.w;
  }
#pragma unroll
  for (int m = 1; m < 64; m <<= 1) { s0 += __shfl_xor(s0, m); s1 += __shfl_xor(s1, m); }
  __shared__ float red0[4], red1[4];
  if ((t & 63) == 0) { red0[t >> 6] = s0; red1[t >> 6] = s1; }
  __syncthreads();
  if (t == 0) {
    out[o0]     = red0[0] + red0[1] + red0[2] + red0[3] + bvec[o0];
    out[o0 + 1] = red1[0] + red1[1] + red1[2] + red1[3] + bvec[o0 + 1];
  }
}

extern "C" void kernel_launch(void* const* d_in, const int* in_sizes, int n_in,
                              void* d_out, int out_size, void* d_ws, size_t ws_size,
                              hipStream_t stream) {
  const float* A  = (const float*)d_in[0];   // [4096,4096] 0/1
  const float* E  = (const float*)d_in[1];   // [4096,4096]
  const float* Wm = (const float*)d_in[2];   // [4096,4096]
  const float* bv = (const float*)d_in[3];   // [4096]
  float* out = (float*)d_out;

  uint32* bitsT = (uint32*)d_ws;                                   // 2 MB (chunk-major)
  float*  e     = (float*)((char*)d_ws + (2u << 20));              // 16 KB
  float*  agg   = (float*)((char*)d_ws + (2u << 20) + 16384);      // 16 KB

  prep_kernel<<<NN + NN / 2, NTHR, 0, stream>>>(A, E, bitsT, e, agg);
  cnt_agg_kernel<<<dim3(NN / STRIPJ, NN / TI), NTHR, 0, stream>>>(bitsT, e, agg);
  matvec_kernel<<<NN / 2, NTHR, 0, stream>>>(Wm, bv, agg, out);
}